// Round 14
// baseline (322.360 us; speedup 1.0000x reference)
//
#include <hip/hip_runtime.h>

#define NN 50000
#define NHEADS 16
#define NGRAPH 128
#define NEDGE 800000
#define NEP (NEDGE + NN)

// bucketed CSR build
#define EPB 2048
#define NBLK 416            // ceil(NEP / EPB)
#define NBUK 391            // ceil(NN / 128), bucket = dst >> 7
#define CASTB 3125          // NN*16/256
#define WTB 192             // 3 * 128*128 / 256
#define WASB 48             // 3 * 32*128 / 256

typedef float4 f4;
typedef __attribute__((ext_vector_type(4))) float f32x4;
typedef __attribute__((ext_vector_type(8))) short s8;   // 8 bf16 (4 VGPRs)

__device__ inline unsigned short f2b(float f) {
  union { float f; unsigned u; } v; v.f = f;
  unsigned r = v.u + 0x7FFFu + ((v.u >> 16) & 1u);   // RNE
  return (unsigned short)(r >> 16);
}
__device__ inline float b2f(unsigned u16) {          // low 16 bits = bf16
  union { unsigned u; float f; } v; v.u = u16 << 16;
  return v.f;
}
__device__ inline float blo(unsigned u) {
  union { unsigned u; float f; } v; v.u = u << 16;
  return v.f;
}
__device__ inline float bhi(unsigned u) {
  union { unsigned u; float f; } v; v.u = u & 0xffff0000u;
  return v.f;
}

// ---------------- front: bucket histogram | x cast | W^T + Was/Wad | graph bounds ----------------

__global__ __launch_bounds__(256) void k_front(const int* __restrict__ ei, int* __restrict__ cntmat,
                                               const float* __restrict__ X, unsigned short* __restrict__ Xb,
                                               const float* __restrict__ W0, const float* __restrict__ W1, const float* __restrict__ W2,
                                               const float* __restrict__ as0, const float* __restrict__ as1, const float* __restrict__ as2,
                                               const float* __restrict__ ad0, const float* __restrict__ ad1, const float* __restrict__ ad2,
                                               unsigned short* __restrict__ T0, unsigned short* __restrict__ T1, unsigned short* __restrict__ T2,
                                               const int* __restrict__ batch, int* __restrict__ gstart) {
  __shared__ int hist[NBUK];
  int b = blockIdx.x, t = threadIdx.x;
  if (b < NBLK) {                        // bucket histogram
    for (int k = t; k < NBUK; k += 256) hist[k] = 0;
    __syncthreads();
    int i0 = b * EPB;
    int i1 = i0 + EPB < NEP ? i0 + EPB : NEP;
    for (int i = i0 + t; i < i1; i += 256) {
      int d = (i < NEDGE) ? ei[NEDGE + i] : (i - NEDGE);
      atomicAdd(&hist[d >> 7], 1);
    }
    __syncthreads();
    for (int k = t; k < NBUK; k += 256) cntmat[b * NBUK + k] = hist[k];
    return;
  }
  int pb = b - NBLK;
  if (pb < CASTB) {                      // cast: 8 elems per thread
    int i = pb * 256 + t;
    const f4* X4 = (const f4*)X;
    f4 a = X4[2 * i], c = X4[2 * i + 1];
    uint4 o;
    o.x = (unsigned)f2b(a.x) | ((unsigned)f2b(a.y) << 16);
    o.y = (unsigned)f2b(a.z) | ((unsigned)f2b(a.w) << 16);
    o.z = (unsigned)f2b(c.x) | ((unsigned)f2b(c.y) << 16);
    o.w = (unsigned)f2b(c.z) | ((unsigned)f2b(c.w) << 16);
    ((uint4*)Xb)[i] = o;
  } else if (pb < CASTB + WTB) {         // W transpose: 3 * 16384 elems
    int idx = (pb - CASTB) * 256 + t;
    int L = idx >> 14, r = idx & 16383;
    int n = r >> 7, kk = r & 127;
    const float* W = (L == 0) ? W0 : (L == 1) ? W1 : W2;
    unsigned short* T = (L == 0) ? T0 : (L == 1) ? T1 : T2;
    T[n * 128 + kk] = f2b(W[kk * 128 + n]);
  } else if (pb < CASTB + WTB + WASB) {  // Was/Wad: 3 * 32 * 128 entries
    int idx = (pb - CASTB - WTB) * 256 + t;
    int L = idx >> 12, r = idx & 4095;
    int h2 = r >> 7, kk = r & 127;
    int h = h2 & 15;
    const float* W = (L == 0) ? W0 : (L == 1) ? W1 : W2;
    const float* av = (h2 < 16) ? ((L == 0) ? as0 : (L == 1) ? as1 : as2)
                                : ((L == 0) ? ad0 : (L == 1) ? ad1 : ad2);
    unsigned short* T = (L == 0) ? T0 : (L == 1) ? T1 : T2;
    float s = 0.f;
#pragma unroll
    for (int c = 0; c < 8; ++c) s += W[kk * 128 + h * 8 + c] * av[h * 8 + c];
    T[(128 + h2) * 128 + kk] = f2b(s);
  } else {                               // graph bounds
    int g = t;
    if (g > NGRAPH) return;
    int lo = 0, hi = NN;
    while (lo < hi) { int mid = (lo + hi) >> 1; if (batch[mid] < g) lo = mid + 1; else hi = mid; }
    gstart[g] = lo;
  }
}

// ---------------- bucketed CSR build (rest) ----------------

__global__ __launch_bounds__(512) void k_bscan(int* __restrict__ cntmat, int* __restrict__ btotal) {
  __shared__ int buf[512];
  int t = threadIdx.x, k = blockIdx.x;
  int v = (t < NBLK) ? cntmat[t * NBUK + k] : 0;
  buf[t] = v;
  __syncthreads();
  for (int off = 1; off < 512; off <<= 1) {
    int y = (t >= off) ? buf[t - off] : 0;
    __syncthreads();
    buf[t] += y;
    __syncthreads();
  }
  if (t < NBLK) cntmat[t * NBUK + k] = buf[t] - v;
  if (t == 511) btotal[k] = buf[511];
}

__global__ __launch_bounds__(512) void k_bbase(const int* __restrict__ btotal, int* __restrict__ bbase) {
  __shared__ int buf[512];
  int t = threadIdx.x;
  int v = (t < NBUK) ? btotal[t] : 0;
  buf[t] = v;
  __syncthreads();
  for (int off = 1; off < 512; off <<= 1) {
    int y = (t >= off) ? buf[t - off] : 0;
    __syncthreads();
    buf[t] += y;
    __syncthreads();
  }
  if (t < NBUK) bbase[t] = buf[t] - v;
  if (t == 511) bbase[NBUK] = buf[511];   // == NEP
}

__global__ __launch_bounds__(256) void k_bscatter(const int* __restrict__ ei, const int* __restrict__ cntmat,
                                                  const int* __restrict__ bbase, unsigned* __restrict__ pairs) {
  __shared__ int cur[NBUK];
  int t = threadIdx.x, b = blockIdx.x;
  for (int k = t; k < NBUK; k += 256) cur[k] = bbase[k] + cntmat[b * NBUK + k];
  __syncthreads();
  int i0 = b * EPB;
  int i1 = i0 + EPB < NEP ? i0 + EPB : NEP;
  for (int i = i0 + t; i < i1; i += 256) {
    int s, d;
    if (i < NEDGE) { s = ei[i]; d = ei[NEDGE + i]; }
    else { s = d = i - NEDGE; }
    int pos = atomicAdd(&cur[d >> 7], 1);
    pairs[pos] = ((unsigned)(d & 127) << 16) | (unsigned)s;   // src < 65536 fits 16 bits
  }
}

__global__ __launch_bounds__(256) void k_bfinal(const unsigned* __restrict__ pairs, const int* __restrict__ bbase,
                                                int* __restrict__ row_off, int* __restrict__ colp) {
  __shared__ int cnt[128];
  __shared__ int buf[128];
  __shared__ int cur[128];
  int t = threadIdx.x, k = blockIdx.x;
  int n0 = k << 7;
  if (t < 128) cnt[t] = 0;
  __syncthreads();
  int p0 = bbase[k], p1 = bbase[k + 1];
  for (int i = p0 + t; i < p1; i += 256) atomicAdd(&cnt[pairs[i] >> 16], 1);
  __syncthreads();
  if (t < 128) buf[t] = cnt[t];
  __syncthreads();
  for (int off = 1; off < 128; off <<= 1) {
    int y = (t < 128 && t >= off) ? buf[t - off] : 0;
    __syncthreads();
    if (t < 128) buf[t] += y;
    __syncthreads();
  }
  if (t < 128) {
    int excl = buf[t] - cnt[t];
    cur[t] = p0 + excl;
    if (n0 + t < NN) row_off[n0 + t] = p0 + excl;
  }
  if (k == NBUK - 1 && t == 0) row_off[NN] = p1;   // == NEP
  __syncthreads();
  for (int i = p0 + t; i < p1; i += 256) {
    unsigned r = pairs[i];
    int pos = atomicAdd(&cur[r >> 16], 1);
    colp[pos] = (int)(r & 0xffffu);
  }
}

// ---------------- GEMM: [Hq | Asq | Ad] = A @ Wt_ext (160 cols), optional fused BN+ReLU on A ----------------
// 16 rows per wave (acc[10] -> ~half VGPR of the 32-row version, 2x wave count for latency hiding).
// Epilogue writes quarter-major tables: Hq[q][N][32], Asq[q][N][4] (q = col>>5 / head>>2)
// so k_agg's per-XCD gather footprint (3.2MB + 0.4MB) fits the 4MB per-XCD L2.

template<int FUSE>
__global__ __launch_bounds__(256) void k_gemm_t(const unsigned short* __restrict__ A, const unsigned short* __restrict__ Wt,
                                                const float* __restrict__ sc, unsigned short* __restrict__ Hq,
                                                unsigned short* __restrict__ Asq, float* __restrict__ Ad) {
  int w = threadIdx.x >> 6, l = threadIdx.x & 63;
  int r0 = blockIdx.x * 64 + w * 16;           // this wave: rows r0..r0+15
  int lr = l & 15, lg = l >> 4;
  f32x4 acc[10];
#pragma unroll
  for (int n = 0; n < 10; ++n) acc[n] = (f32x4){0.f, 0.f, 0.f, 0.f};

#pragma unroll
  for (int ks = 0; ks < 4; ++ks) {
    int koff = ks * 32 + lg * 8;
    s8 a;
    int row = r0 + lr;
    row = (row < NN) ? row : (NN - 1);
    if constexpr (FUSE) {
      f4 s0 = *(const f4*)(sc + koff),       s1 = *(const f4*)(sc + koff + 4);
      f4 h0 = *(const f4*)(sc + 128 + koff), h1 = *(const f4*)(sc + 128 + koff + 4);
      uint4 raw = *(const uint4*)(A + (size_t)row * 128 + koff);
      float v0 = fmaxf(blo(raw.x) * s0.x + h0.x, 0.f);
      float v1 = fmaxf(bhi(raw.x) * s0.y + h0.y, 0.f);
      float v2 = fmaxf(blo(raw.y) * s0.z + h0.z, 0.f);
      float v3 = fmaxf(bhi(raw.y) * s0.w + h0.w, 0.f);
      float v4 = fmaxf(blo(raw.z) * s1.x + h1.x, 0.f);
      float v5 = fmaxf(bhi(raw.z) * s1.y + h1.y, 0.f);
      float v6 = fmaxf(blo(raw.w) * s1.z + h1.z, 0.f);
      float v7 = fmaxf(bhi(raw.w) * s1.w + h1.w, 0.f);
      union { s8 v; uint4 u; } pk;
      pk.u.x = (unsigned)f2b(v0) | ((unsigned)f2b(v1) << 16);
      pk.u.y = (unsigned)f2b(v2) | ((unsigned)f2b(v3) << 16);
      pk.u.z = (unsigned)f2b(v4) | ((unsigned)f2b(v5) << 16);
      pk.u.w = (unsigned)f2b(v6) | ((unsigned)f2b(v7) << 16);
      a = pk.v;
    } else {
      a = *(const s8*)(A + (size_t)row * 128 + koff);
    }
#pragma unroll
    for (int n = 0; n < 10; ++n) {
      s8 b = *(const s8*)(Wt + (size_t)(n * 16 + lr) * 128 + koff);
      acc[n] = __builtin_amdgcn_mfma_f32_16x16x32_bf16(a, b, acc[n], 0, 0, 0);
    }
  }

  // C/D layout: col = lane&15, row = (lane>>4)*4 + reg   [verified m89/m91]
  int rowb = r0 + lg * 4;
#pragma unroll
  for (int n = 0; n < 8; ++n) {
    int colb = n * 16 + lr;
    int q = colb >> 5, cq = colb & 31;
#pragma unroll
    for (int reg = 0; reg < 4; ++reg) {
      int row = rowb + reg;
      if (row < NN) Hq[(size_t)q * NN * 32 + (size_t)row * 32 + cq] = f2b(acc[n][reg]);
    }
  }
  // tile 8: As (bf16, quarter-major); tile 9: Ad (fp32)
  int hq = lr >> 2, hl = lr & 3;
#pragma unroll
  for (int reg = 0; reg < 4; ++reg) {
    int row = rowb + reg;
    if (row < NN) {
      Asq[(size_t)hq * NN * 4 + (size_t)row * 4 + hl] = f2b(acc[8][reg]);
      Ad[row * 16 + lr] = acc[9][reg];
    }
  }
}

// ---------------- aggregation: quarter-split across XCD pairs, L2-resident tables ----------------
// Block handles 32 nodes x ONE 32-channel quarter (4 heads). quarter = (blockIdx%8)>>1 ->
// XCD pair {2q, 2q+1} via round-robin dispatch; each XCD's gather footprint = Hq quarter
// (3.2MB) + Asq quarter (0.4MB) < 4MB L2 -> gathers become L2 hits after cold fill.
// 8 lanes/node = 4 heads x 2 edge-parities; per edge 4 lanes read 64B contiguous.
// exp without max-shift (shift-invariant, |e|~3). GAT bias absorbed by next BN's mean-sub.

__global__ __launch_bounds__(256, 4) void k_agg(const unsigned short* __restrict__ HqB, const unsigned short* __restrict__ AsqB,
                                                const float* __restrict__ Ad,
                                                const int* __restrict__ row_off, const int* __restrict__ col,
                                                unsigned short* __restrict__ Vb) {
  int b = blockIdx.x;
  int q = (b & 7) >> 1;                  // quarter -> XCD pair
  int nb = (b >> 3) * 2 + (b & 1);       // node-block within quarter
  int t = threadIdx.x;
  int node = nb * 32 + (t >> 3);
  if (node >= NN) return;
  const unsigned short* Hq = HqB + (size_t)q * NN * 32;
  const unsigned short* Aq = AsqB + (size_t)q * NN * 4;
  int l = t & 7;
  int hl = l & 3, par = l >> 2;
  int h = q * 4 + hl;
  int e0 = row_off[node], e1 = row_off[node + 1];
  float adh = Ad[node * 16 + h];
  float den = 0.f;
  float acc[8] = {0.f, 0.f, 0.f, 0.f, 0.f, 0.f, 0.f, 0.f};
  int j = e0 + par;
  for (; j + 14 < e1; j += 16) {   // 8 edges per lane in flight
    int s[8];
#pragma unroll
    for (int p = 0; p < 8; ++p) s[p] = col[j + 2 * p];
    float a[8];
#pragma unroll
    for (int p = 0; p < 8; ++p) a[p] = b2f(Aq[s[p] * 4 + hl]);
    uint4 pp[8];
#pragma unroll
    for (int p = 0; p < 8; ++p) pp[p] = *(const uint4*)(Hq + (size_t)s[p] * 32 + hl * 8);
#pragma unroll
    for (int p = 0; p < 8; ++p) {
      float e = a[p] + adh;
      e = (e > 0.f) ? e : 0.2f * e;
      a[p] = __expf(e);
      den += a[p];
    }
#pragma unroll
    for (int p = 0; p < 8; ++p) {
      acc[0] += a[p] * blo(pp[p].x); acc[1] += a[p] * bhi(pp[p].x);
      acc[2] += a[p] * blo(pp[p].y); acc[3] += a[p] * bhi(pp[p].y);
      acc[4] += a[p] * blo(pp[p].z); acc[5] += a[p] * bhi(pp[p].z);
      acc[6] += a[p] * blo(pp[p].w); acc[7] += a[p] * bhi(pp[p].w);
    }
  }
  for (; j + 6 < e1; j += 8) {     // 4-deep tail
    int s[4];
#pragma unroll
    for (int p = 0; p < 4; ++p) s[p] = col[j + 2 * p];
    float a[4];
#pragma unroll
    for (int p = 0; p < 4; ++p) a[p] = b2f(Aq[s[p] * 4 + hl]);
    uint4 pp[4];
#pragma unroll
    for (int p = 0; p < 4; ++p) pp[p] = *(const uint4*)(Hq + (size_t)s[p] * 32 + hl * 8);
#pragma unroll
    for (int p = 0; p < 4; ++p) {
      float e = a[p] + adh;
      e = (e > 0.f) ? e : 0.2f * e;
      a[p] = __expf(e);
      den += a[p];
    }
#pragma unroll
    for (int p = 0; p < 4; ++p) {
      acc[0] += a[p] * blo(pp[p].x); acc[1] += a[p] * bhi(pp[p].x);
      acc[2] += a[p] * blo(pp[p].y); acc[3] += a[p] * bhi(pp[p].y);
      acc[4] += a[p] * blo(pp[p].z); acc[5] += a[p] * bhi(pp[p].z);
      acc[6] += a[p] * blo(pp[p].w); acc[7] += a[p] * bhi(pp[p].w);
    }
  }
  for (; j < e1; j += 2) {
    int s0 = col[j];
    float a0 = b2f(Aq[s0 * 4 + hl]) + adh;
    uint4 p0 = *(const uint4*)(Hq + (size_t)s0 * 32 + hl * 8);
    a0 = (a0 > 0.f) ? a0 : 0.2f * a0;
    float x0 = __expf(a0);
    den += x0;
    acc[0] += x0 * blo(p0.x); acc[1] += x0 * bhi(p0.x);
    acc[2] += x0 * blo(p0.y); acc[3] += x0 * bhi(p0.y);
    acc[4] += x0 * blo(p0.z); acc[5] += x0 * bhi(p0.z);
    acc[6] += x0 * blo(p0.w); acc[7] += x0 * bhi(p0.w);
  }
  // cross-parity reduce (lane ^ 4 within the node's 8-lane group)
  den += __shfl_xor(den, 4);
#pragma unroll
  for (int k = 0; k < 8; ++k) acc[k] += __shfl_xor(acc[k], 4);
  if (par == 0) {
    float inv = 1.f / (den + 1e-16f);
    uint4 o;
    o.x = (unsigned)f2b(acc[0] * inv) | ((unsigned)f2b(acc[1] * inv) << 16);
    o.y = (unsigned)f2b(acc[2] * inv) | ((unsigned)f2b(acc[3] * inv) << 16);
    o.z = (unsigned)f2b(acc[4] * inv) | ((unsigned)f2b(acc[5] * inv) << 16);
    o.w = (unsigned)f2b(acc[6] * inv) | ((unsigned)f2b(acc[7] * inv) << 16);
    *(uint4*)(Vb + (size_t)node * 128 + q * 32 + hl * 8) = o;
  }
}

// ---------------- BatchNorm stats: atomic-free two-stage reduce over bf16 V ----------------

#define BN_CHUNK 391   // 128 * 391 = 50048 >= NN

__global__ __launch_bounds__(256) void k_bnreduce(const unsigned short* __restrict__ Vb, float* __restrict__ partS, float* __restrict__ partQ) {
  int t = threadIdx.x;
  int c4 = t & 31, rs = t >> 5;               // 32 channel-quads x 8 row-streams
  int r0 = blockIdx.x * BN_CHUNK + rs;
  int rend = blockIdx.x * BN_CHUNK + BN_CHUNK;
  if (rend > NN) rend = NN;
  float s0 = 0.f, s1 = 0.f, s2 = 0.f, s3 = 0.f;
  float q0 = 0.f, q1 = 0.f, q2 = 0.f, q3 = 0.f;
  for (int r = r0; r < rend; r += 8) {
    uint2 p = *(const uint2*)(Vb + (size_t)r * 128 + c4 * 4);
    float v0 = blo(p.x), v1 = bhi(p.x);
    float v2 = blo(p.y), v3 = bhi(p.y);
    s0 += v0; s1 += v1; s2 += v2; s3 += v3;
    q0 += v0 * v0; q1 += v1 * v1; q2 += v2 * v2; q3 += v3 * v3;
  }
  __shared__ float sm[8][32][8];
  sm[rs][c4][0] = s0; sm[rs][c4][1] = s1; sm[rs][c4][2] = s2; sm[rs][c4][3] = s3;
  sm[rs][c4][4] = q0; sm[rs][c4][5] = q1; sm[rs][c4][6] = q2; sm[rs][c4][7] = q3;
  __syncthreads();
  if (t < 32) {
#pragma unroll
    for (int k = 0; k < 4; ++k) {
      float S = 0.f, Q = 0.f;
#pragma unroll
      for (int r = 0; r < 8; ++r) { S += sm[r][t][k]; Q += sm[r][t][4 + k]; }
      partS[blockIdx.x * 128 + t * 4 + k] = S;
      partQ[blockIdx.x * 128 + t * 4 + k] = Q;
    }
  }
}

__global__ __launch_bounds__(512) void k_bnfin(const float* __restrict__ partS, const float* __restrict__ partQ,
                                               const float* __restrict__ gam, const float* __restrict__ bet,
                                               float* __restrict__ sc) {
  int t = threadIdx.x;
  int c = t & 127, q = (t >> 7) & 1, hf = t >> 8;
  const float* src = q ? partQ : partS;
  float s = 0.f;
#pragma unroll 8
  for (int i = hf * 64; i < hf * 64 + 64; ++i) s += src[i * 128 + c];
  __shared__ float sm[512];
  sm[t] = s;
  __syncthreads();
  if (t < 128) {
    float S = sm[t] + sm[t + 256];
    float Q = sm[t + 128] + sm[t + 384];
    float mean = S * (1.f / NN);
    float var = fmaxf(Q * (1.f / NN) - mean * mean, 0.f);
    float sg = gam[t] * rsqrtf(var + 1e-5f);
    sc[t] = sg;
    sc[128 + t] = bet[t] - mean * sg;
  }
}

// ---------------- pooling (BN+ReLU inline, atomic-free partials) + final ----------------

__global__ __launch_bounds__(256) void k_pool(const unsigned short* __restrict__ Vb, const float* __restrict__ sc,
                                              const int* __restrict__ gstart, float* __restrict__ pp) {
  int g = blockIdx.x >> 2, chunk = blockIdx.x & 3;
  int t = threadIdx.x;
  int c4 = t & 31, rs = t >> 5;
  f4 s = ((const f4*)sc)[c4], sh = ((const f4*)sc)[32 + c4];
  int r0 = gstart[g], r1 = gstart[g + 1];
  float s0 = 0.f, s1 = 0.f, s2 = 0.f, s3 = 0.f;
  for (int r = r0 + chunk + 4 * rs; r < r1; r += 32) {
    uint2 p = *(const uint2*)(Vb + (size_t)r * 128 + c4 * 4);
    s0 += fmaxf(blo(p.x) * s.x + sh.x, 0.f);
    s1 += fmaxf(bhi(p.x) * s.y + sh.y, 0.f);
    s2 += fmaxf(blo(p.y) * s.z + sh.z, 0.f);
    s3 += fmaxf(bhi(p.y) * s.w + sh.w, 0.f);
  }
  __shared__ float sm[8][32][4];
  sm[rs][c4][0] = s0; sm[rs][c4][1] = s1; sm[rs][c4][2] = s2; sm[rs][c4][3] = s3;
  __syncthreads();
  if (t < 32) {
#pragma unroll
    for (int k = 0; k < 4; ++k) {
      float S = 0.f;
#pragma unroll
      for (int r = 0; r < 8; ++r) S += sm[r][t][k];
      pp[(size_t)blockIdx.x * 128 + t * 4 + k] = S;   // partial per (g,chunk)
    }
  }
}

__global__ __launch_bounds__(256) void k_final(const float* __restrict__ pp, const int* __restrict__ gstart,
                                               const float* __restrict__ Wl, const float* __restrict__ bl,
                                               const float* __restrict__ g4, const float* __restrict__ b4,
                                               float* __restrict__ out) {
  int t = threadIdx.x;
  int g = t >> 1, cls = t & 1;
  float cnt = fmaxf((float)(gstart[g + 1] - gstart[g]), 1.f);
  float inv = 1.f / cnt;
  float z = bl[cls];
  for (int f = 0; f < 128; ++f) {
    float ps = pp[(size_t)(g * 4 + 0) * 128 + f] + pp[(size_t)(g * 4 + 1) * 128 + f]
             + pp[(size_t)(g * 4 + 2) * 128 + f] + pp[(size_t)(g * 4 + 3) * 128 + f];
    z += ps * inv * Wl[f * 2 + cls] + ps * Wl[(128 + f) * 2 + cls];
  }
  __shared__ float zs[256];
  __shared__ float st[4];
  zs[t] = z;
  __syncthreads();
  if (t < 2) {
    float s = 0.f, s2 = 0.f;
    for (int gg = 0; gg < 128; ++gg) { float v = zs[gg * 2 + t]; s += v; s2 += v * v; }
    float mean = s * (1.f / 128.f);
    float var = s2 * (1.f / 128.f) - mean * mean;
    var = fmaxf(var, 0.f);
    float sc = g4[t] * rsqrtf(var + 1e-5f);
    st[t] = sc; st[2 + t] = b4[t] - mean * sc;
  }
  __syncthreads();
  out[t] = zs[t] * st[cls] + st[2 + cls];
}

// ---------------- host launcher ----------------

extern "C" void kernel_launch(void* const* d_in, const int* in_sizes, int n_in,
                              void* d_out, int out_size, void* d_ws, size_t ws_size,
                              hipStream_t stream) {
  const float* x     = (const float*)d_in[0];
  const int*   ei    = (const int*)d_in[1];
  const int*   batch = (const int*)d_in[2];
  const float* W[3]    = {(const float*)d_in[3],  (const float*)d_in[9],  (const float*)d_in[15]};
  const float* asrc[3] = {(const float*)d_in[5],  (const float*)d_in[11], (const float*)d_in[17]};
  const float* adst[3] = {(const float*)d_in[6],  (const float*)d_in[12], (const float*)d_in[18]};
  const float* gam[3]  = {(const float*)d_in[7],  (const float*)d_in[13], (const float*)d_in[19]};
  const float* bet[3]  = {(const float*)d_in[8],  (const float*)d_in[14], (const float*)d_in[20]};
  const float* Wl    = (const float*)d_in[21];
  const float* bl    = (const float*)d_in[22];
  const float* g4    = (const float*)d_in[23];
  const float* beta4 = (const float*)d_in[24];

  char* ws = (char*)d_ws;
  size_t off = 0;
  auto alloc = [&](size_t bytes) -> void* {
    void* p = (void*)(ws + off);
    off += (bytes + 255) & ~(size_t)255;
    return p;
  };

  int* row_off  = (int*)alloc((size_t)(NN + 1) * 4);
  int* col      = (int*)alloc((size_t)NEP * 4);
  int* cntmat   = (int*)alloc((size_t)NBLK * NBUK * 4);
  int* btotal   = (int*)alloc((size_t)NBUK * 4);
  int* bbase    = (int*)alloc((size_t)(NBUK + 1) * 4);
  unsigned* pairs = (unsigned*)alloc((size_t)NEP * 4);
  unsigned short* Xb = (unsigned short*)alloc((size_t)NN * 128 * 2);   // layer-0 GEMM input (bf16)
  unsigned short* Hq = (unsigned short*)alloc((size_t)NN * 128 * 2);   // GEMM output, quarter-major [4][N][32]
  unsigned short* Vb = (unsigned short*)alloc((size_t)NN * 128 * 2);   // agg output, pre-BN (bf16)
  unsigned short* Asq = (unsigned short*)alloc((size_t)NN * 16 * 2);   // quarter-major [4][N][4]
  float* Ad     = (float*)alloc((size_t)NN * 16 * 4);
  unsigned short* Wt0 = (unsigned short*)alloc((size_t)160 * 128 * 2);
  unsigned short* Wt1 = (unsigned short*)alloc((size_t)160 * 128 * 2);
  unsigned short* Wt2 = (unsigned short*)alloc((size_t)160 * 128 * 2);
  const unsigned short* Wt[3] = {Wt0, Wt1, Wt2};
  float* partS  = (float*)alloc(128 * 128 * 4);
  float* partQ  = (float*)alloc(128 * 128 * 4);
  float* bn_sc  = (float*)alloc(256 * 4);
  float* pp     = (float*)alloc((size_t)NGRAPH * 4 * 128 * 4);
  int* gstart   = (int*)alloc((size_t)(NGRAPH + 1) * 4);

  // ---- front: bucket histogram + all prep work (independent) in one launch ----
  k_front<<<NBLK + CASTB + WTB + WASB + 1, 256, 0, stream>>>(ei, cntmat, x, Xb, W[0], W[1], W[2],
                                                             asrc[0], asrc[1], asrc[2], adst[0], adst[1], adst[2],
                                                             Wt0, Wt1, Wt2, batch, gstart);
  k_bscan<<<NBUK, 512, 0, stream>>>(cntmat, btotal);
  k_bbase<<<1, 512, 0, stream>>>(btotal, bbase);
  k_bscatter<<<NBLK, 256, 0, stream>>>(ei, cntmat, bbase, pairs);
  k_bfinal<<<NBUK, 256, 0, stream>>>(pairs, bbase, row_off, col);

  for (int L = 0; L < 3; ++L) {
    if (L == 0)
      k_gemm_t<0><<<(NN + 63) / 64, 256, 0, stream>>>(Xb, Wt[L], nullptr, Hq, Asq, Ad);
    else
      k_gemm_t<1><<<(NN + 63) / 64, 256, 0, stream>>>(Vb, Wt[L], bn_sc, Hq, Asq, Ad);
    // 1563 node-blocks per quarter (32 nodes each); grid 8-aligned for XCD steering
    k_agg<<<6256, 256, 0, stream>>>(Hq, Asq, Ad, row_off, col, Vb);
    k_bnreduce<<<128, 256, 0, stream>>>(Vb, partS, partQ);
    k_bnfin<<<1, 512, 0, stream>>>(partS, partQ, gam[L], bet[L], bn_sc);
  }

  k_pool<<<NGRAPH * 4, 256, 0, stream>>>(Vb, bn_sc, gstart, pp);   // BN+ReLU fused, atomic-free
  k_final<<<1, 256, 0, stream>>>(pp, gstart, Wl, bl, g4, beta4, (float*)d_out);
}

// Round 15
// 281.995 us; speedup vs baseline: 1.1431x; 1.1431x over previous
//
#include <hip/hip_runtime.h>

#define NN 50000
#define NHEADS 16
#define NGRAPH 128
#define NEDGE 800000
#define NEP (NEDGE + NN)

// bucketed CSR build
#define EPB 2048
#define NBLK 416            // ceil(NEP / EPB)
#define NBUK 391            // ceil(NN / 128), bucket = dst >> 7
#define CASTB 3125          // NN*16/256
#define WTB 192             // 3 * 128*128 / 256
#define WASB 48             // 3 * 32*128 / 256

typedef float4 f4;
typedef __attribute__((ext_vector_type(4))) float f32x4;
typedef __attribute__((ext_vector_type(8))) short s8;   // 8 bf16 (4 VGPRs)

__device__ inline unsigned short f2b(float f) {
  union { float f; unsigned u; } v; v.f = f;
  unsigned r = v.u + 0x7FFFu + ((v.u >> 16) & 1u);   // RNE
  return (unsigned short)(r >> 16);
}
__device__ inline float b2f(unsigned u16) {          // low 16 bits = bf16
  union { unsigned u; float f; } v; v.u = u16 << 16;
  return v.f;
}
__device__ inline float blo(unsigned u) {
  union { unsigned u; float f; } v; v.u = u << 16;
  return v.f;
}
__device__ inline float bhi(unsigned u) {
  union { unsigned u; float f; } v; v.u = u & 0xffff0000u;
  return v.f;
}

// ---------------- front: bucket histogram | x cast | W^T + Was/Wad | graph bounds ----------------

__global__ __launch_bounds__(256) void k_front(const int* __restrict__ ei, int* __restrict__ cntmat,
                                               const float* __restrict__ X, unsigned short* __restrict__ Xb,
                                               const float* __restrict__ W0, const float* __restrict__ W1, const float* __restrict__ W2,
                                               const float* __restrict__ as0, const float* __restrict__ as1, const float* __restrict__ as2,
                                               const float* __restrict__ ad0, const float* __restrict__ ad1, const float* __restrict__ ad2,
                                               unsigned short* __restrict__ T0, unsigned short* __restrict__ T1, unsigned short* __restrict__ T2,
                                               const int* __restrict__ batch, int* __restrict__ gstart) {
  __shared__ int hist[NBUK];
  int b = blockIdx.x, t = threadIdx.x;
  if (b < NBLK) {                        // bucket histogram
    for (int k = t; k < NBUK; k += 256) hist[k] = 0;
    __syncthreads();
    int i0 = b * EPB;
    int i1 = i0 + EPB < NEP ? i0 + EPB : NEP;
    for (int i = i0 + t; i < i1; i += 256) {
      int d = (i < NEDGE) ? ei[NEDGE + i] : (i - NEDGE);
      atomicAdd(&hist[d >> 7], 1);
    }
    __syncthreads();
    for (int k = t; k < NBUK; k += 256) cntmat[b * NBUK + k] = hist[k];
    return;
  }
  int pb = b - NBLK;
  if (pb < CASTB) {                      // cast: 8 elems per thread
    int i = pb * 256 + t;
    const f4* X4 = (const f4*)X;
    f4 a = X4[2 * i], c = X4[2 * i + 1];
    uint4 o;
    o.x = (unsigned)f2b(a.x) | ((unsigned)f2b(a.y) << 16);
    o.y = (unsigned)f2b(a.z) | ((unsigned)f2b(a.w) << 16);
    o.z = (unsigned)f2b(c.x) | ((unsigned)f2b(c.y) << 16);
    o.w = (unsigned)f2b(c.z) | ((unsigned)f2b(c.w) << 16);
    ((uint4*)Xb)[i] = o;
  } else if (pb < CASTB + WTB) {         // W transpose: 3 * 16384 elems
    int idx = (pb - CASTB) * 256 + t;
    int L = idx >> 14, r = idx & 16383;
    int n = r >> 7, kk = r & 127;
    const float* W = (L == 0) ? W0 : (L == 1) ? W1 : W2;
    unsigned short* T = (L == 0) ? T0 : (L == 1) ? T1 : T2;
    T[n * 128 + kk] = f2b(W[kk * 128 + n]);
  } else if (pb < CASTB + WTB + WASB) {  // Was/Wad: 3 * 32 * 128 entries
    int idx = (pb - CASTB - WTB) * 256 + t;
    int L = idx >> 12, r = idx & 4095;
    int h2 = r >> 7, kk = r & 127;
    int h = h2 & 15;
    const float* W = (L == 0) ? W0 : (L == 1) ? W1 : W2;
    const float* av = (h2 < 16) ? ((L == 0) ? as0 : (L == 1) ? as1 : as2)
                                : ((L == 0) ? ad0 : (L == 1) ? ad1 : ad2);
    unsigned short* T = (L == 0) ? T0 : (L == 1) ? T1 : T2;
    float s = 0.f;
#pragma unroll
    for (int c = 0; c < 8; ++c) s += W[kk * 128 + h * 8 + c] * av[h * 8 + c];
    T[(128 + h2) * 128 + kk] = f2b(s);
  } else {                               // graph bounds
    int g = t;
    if (g > NGRAPH) return;
    int lo = 0, hi = NN;
    while (lo < hi) { int mid = (lo + hi) >> 1; if (batch[mid] < g) lo = mid + 1; else hi = mid; }
    gstart[g] = lo;
  }
}

// ---------------- bucketed CSR build (rest) ----------------

__global__ __launch_bounds__(512) void k_bscan(int* __restrict__ cntmat, int* __restrict__ btotal) {
  __shared__ int buf[512];
  int t = threadIdx.x, k = blockIdx.x;
  int v = (t < NBLK) ? cntmat[t * NBUK + k] : 0;
  buf[t] = v;
  __syncthreads();
  for (int off = 1; off < 512; off <<= 1) {
    int y = (t >= off) ? buf[t - off] : 0;
    __syncthreads();
    buf[t] += y;
    __syncthreads();
  }
  if (t < NBLK) cntmat[t * NBUK + k] = buf[t] - v;
  if (t == 511) btotal[k] = buf[511];
}

__global__ __launch_bounds__(512) void k_bbase(const int* __restrict__ btotal, int* __restrict__ bbase) {
  __shared__ int buf[512];
  int t = threadIdx.x;
  int v = (t < NBUK) ? btotal[t] : 0;
  buf[t] = v;
  __syncthreads();
  for (int off = 1; off < 512; off <<= 1) {
    int y = (t >= off) ? buf[t - off] : 0;
    __syncthreads();
    buf[t] += y;
    __syncthreads();
  }
  if (t < NBUK) bbase[t] = buf[t] - v;
  if (t == 511) bbase[NBUK] = buf[511];   // == NEP
}

__global__ __launch_bounds__(256) void k_bscatter(const int* __restrict__ ei, const int* __restrict__ cntmat,
                                                  const int* __restrict__ bbase, unsigned* __restrict__ pairs) {
  __shared__ int cur[NBUK];
  int t = threadIdx.x, b = blockIdx.x;
  for (int k = t; k < NBUK; k += 256) cur[k] = bbase[k] + cntmat[b * NBUK + k];
  __syncthreads();
  int i0 = b * EPB;
  int i1 = i0 + EPB < NEP ? i0 + EPB : NEP;
  for (int i = i0 + t; i < i1; i += 256) {
    int s, d;
    if (i < NEDGE) { s = ei[i]; d = ei[NEDGE + i]; }
    else { s = d = i - NEDGE; }
    int pos = atomicAdd(&cur[d >> 7], 1);
    pairs[pos] = ((unsigned)(d & 127) << 16) | (unsigned)s;   // src < 65536 fits 16 bits
  }
}

__global__ __launch_bounds__(256) void k_bfinal(const unsigned* __restrict__ pairs, const int* __restrict__ bbase,
                                                int* __restrict__ row_off, int* __restrict__ colp) {
  __shared__ int cnt[128];
  __shared__ int buf[128];
  __shared__ int cur[128];
  int t = threadIdx.x, k = blockIdx.x;
  int n0 = k << 7;
  if (t < 128) cnt[t] = 0;
  __syncthreads();
  int p0 = bbase[k], p1 = bbase[k + 1];
  for (int i = p0 + t; i < p1; i += 256) atomicAdd(&cnt[pairs[i] >> 16], 1);
  __syncthreads();
  if (t < 128) buf[t] = cnt[t];
  __syncthreads();
  for (int off = 1; off < 128; off <<= 1) {
    int y = (t < 128 && t >= off) ? buf[t - off] : 0;
    __syncthreads();
    if (t < 128) buf[t] += y;
    __syncthreads();
  }
  if (t < 128) {
    int excl = buf[t] - cnt[t];
    cur[t] = p0 + excl;
    if (n0 + t < NN) row_off[n0 + t] = p0 + excl;
  }
  if (k == NBUK - 1 && t == 0) row_off[NN] = p1;   // == NEP
  __syncthreads();
  for (int i = p0 + t; i < p1; i += 256) {
    unsigned r = pairs[i];
    int pos = atomicAdd(&cur[r >> 16], 1);
    colp[pos] = (int)(r & 0xffffu);
  }
}

// ---------------- GEMM: [Hb | As | Ad] = A @ Wt_ext (160 cols), optional fused BN+ReLU on A ----------------

template<int FUSE>
__global__ __launch_bounds__(256) void k_gemm_t(const unsigned short* __restrict__ A, const unsigned short* __restrict__ Wt,
                                                const float* __restrict__ sc, unsigned short* __restrict__ Hb,
                                                unsigned short* __restrict__ Asb, float* __restrict__ Ad) {
  int w = threadIdx.x >> 6, l = threadIdx.x & 63;
  int r0 = blockIdx.x * 128 + w * 32;          // this wave: rows r0..r0+31
  int lr = l & 15, lg = l >> 4;
  f32x4 acc[2][10];
#pragma unroll
  for (int m = 0; m < 2; ++m)
#pragma unroll
    for (int n = 0; n < 10; ++n) acc[m][n] = (f32x4){0.f, 0.f, 0.f, 0.f};

#pragma unroll
  for (int ks = 0; ks < 4; ++ks) {
    int koff = ks * 32 + lg * 8;
    s8 a[2];
    if constexpr (FUSE) {
      f4 s0 = *(const f4*)(sc + koff),       s1 = *(const f4*)(sc + koff + 4);
      f4 h0 = *(const f4*)(sc + 128 + koff), h1 = *(const f4*)(sc + 128 + koff + 4);
#pragma unroll
      for (int m = 0; m < 2; ++m) {
        int row = r0 + m * 16 + lr;
        row = (row < NN) ? row : (NN - 1);
        uint4 raw = *(const uint4*)(A + (size_t)row * 128 + koff);
        float v0 = fmaxf(blo(raw.x) * s0.x + h0.x, 0.f);
        float v1 = fmaxf(bhi(raw.x) * s0.y + h0.y, 0.f);
        float v2 = fmaxf(blo(raw.y) * s0.z + h0.z, 0.f);
        float v3 = fmaxf(bhi(raw.y) * s0.w + h0.w, 0.f);
        float v4 = fmaxf(blo(raw.z) * s1.x + h1.x, 0.f);
        float v5 = fmaxf(bhi(raw.z) * s1.y + h1.y, 0.f);
        float v6 = fmaxf(blo(raw.w) * s1.z + h1.z, 0.f);
        float v7 = fmaxf(bhi(raw.w) * s1.w + h1.w, 0.f);
        union { s8 v; uint4 u; } pk;
        pk.u.x = (unsigned)f2b(v0) | ((unsigned)f2b(v1) << 16);
        pk.u.y = (unsigned)f2b(v2) | ((unsigned)f2b(v3) << 16);
        pk.u.z = (unsigned)f2b(v4) | ((unsigned)f2b(v5) << 16);
        pk.u.w = (unsigned)f2b(v6) | ((unsigned)f2b(v7) << 16);
        a[m] = pk.v;
      }
    } else {
#pragma unroll
      for (int m = 0; m < 2; ++m) {
        int row = r0 + m * 16 + lr;
        row = (row < NN) ? row : (NN - 1);
        a[m] = *(const s8*)(A + (size_t)row * 128 + koff);
      }
    }
#pragma unroll
    for (int n = 0; n < 10; ++n) {
      s8 b = *(const s8*)(Wt + (size_t)(n * 16 + lr) * 128 + koff);
#pragma unroll
      for (int m = 0; m < 2; ++m)
        acc[m][n] = __builtin_amdgcn_mfma_f32_16x16x32_bf16(a[m], b, acc[m][n], 0, 0, 0);
    }
  }

  // C/D layout: col = lane&15, row = (lane>>4)*4 + reg   [verified m89/m91]
#pragma unroll
  for (int m = 0; m < 2; ++m) {
    int rowb = r0 + m * 16 + lg * 4;
#pragma unroll
    for (int n = 0; n < 8; ++n) {
      int colb = n * 16 + lr;
#pragma unroll
      for (int reg = 0; reg < 4; ++reg) {
        int row = rowb + reg;
        if (row < NN) Hb[(size_t)row * 128 + colb] = f2b(acc[m][n][reg]);
      }
    }
    // tiles 8/9: As (bf16) and Ad (fp32), col = head = lr
#pragma unroll
    for (int reg = 0; reg < 4; ++reg) {
      int row = rowb + reg;
      if (row < NN) {
        Asb[row * 16 + lr] = f2b(acc[m][8][reg]);
        Ad[row * 16 + lr] = acc[m][9][reg];
      }
    }
  }
}

// ---------------- aggregation: channel-split across XCD groups (best measured config) ----------------
// Block handles 16 nodes x ONE 64-channel half. half = (blockIdx%8)>=4 -> via the
// round-robin block->XCD dispatch, XCDs 0-3 fetch only channels 0-63 of H, XCDs 4-7 only
// 64-127: per-XCD compulsory L2 fill of Hb halves. R14 experiment proved further
// byte-cutting (quarter-split) doesn't help: kernel is VMEM-issue/latency bound here.

__global__ __launch_bounds__(256, 4) void k_agg(const unsigned short* __restrict__ Hb, const unsigned short* __restrict__ Asb,
                                                const float* __restrict__ Ad,
                                                const int* __restrict__ row_off, const int* __restrict__ col,
                                                unsigned short* __restrict__ Vb) {
  int b = blockIdx.x;
  int half = (b >> 2) & 1;               // b%8: 0-3 -> half 0, 4-7 -> half 1
  int nb = (b >> 3) * 4 + (b & 3);       // node-block within half
  if (nb >= 3125) return;                // 3125 * 16 == 50000
  int t = threadIdx.x;
  int node = nb * 16 + (t >> 4);
  int l = t & 15;
  int h = half * 8 + (l & 7);            // this lane's head
  int par = l >> 3;                      // edge parity
  int e0 = row_off[node], e1 = row_off[node + 1];
  float adh = Ad[node * 16 + h];
  float den = 0.f;
  float acc[8] = {0.f, 0.f, 0.f, 0.f, 0.f, 0.f, 0.f, 0.f};
  int j = e0 + par;
  for (; j + 14 < e1; j += 16) {   // 8 edges per lane in flight
    int s[8];
#pragma unroll
    for (int q = 0; q < 8; ++q) s[q] = col[j + 2 * q];
    float a[8];
#pragma unroll
    for (int q = 0; q < 8; ++q) a[q] = b2f(Asb[s[q] * 16 + h]);
    uint4 p[8];
#pragma unroll
    for (int q = 0; q < 8; ++q) p[q] = *(const uint4*)(Hb + (size_t)s[q] * 128 + h * 8);
#pragma unroll
    for (int q = 0; q < 8; ++q) {
      float e = a[q] + adh;
      e = (e > 0.f) ? e : 0.2f * e;
      a[q] = __expf(e);
      den += a[q];
    }
#pragma unroll
    for (int q = 0; q < 8; ++q) {
      acc[0] += a[q] * blo(p[q].x); acc[1] += a[q] * bhi(p[q].x);
      acc[2] += a[q] * blo(p[q].y); acc[3] += a[q] * bhi(p[q].y);
      acc[4] += a[q] * blo(p[q].z); acc[5] += a[q] * bhi(p[q].z);
      acc[6] += a[q] * blo(p[q].w); acc[7] += a[q] * bhi(p[q].w);
    }
  }
  for (; j + 6 < e1; j += 8) {     // 4-deep tail
    int s[4];
#pragma unroll
    for (int q = 0; q < 4; ++q) s[q] = col[j + 2 * q];
    float a[4];
#pragma unroll
    for (int q = 0; q < 4; ++q) a[q] = b2f(Asb[s[q] * 16 + h]);
    uint4 p[4];
#pragma unroll
    for (int q = 0; q < 4; ++q) p[q] = *(const uint4*)(Hb + (size_t)s[q] * 128 + h * 8);
#pragma unroll
    for (int q = 0; q < 4; ++q) {
      float e = a[q] + adh;
      e = (e > 0.f) ? e : 0.2f * e;
      a[q] = __expf(e);
      den += a[q];
    }
#pragma unroll
    for (int q = 0; q < 4; ++q) {
      acc[0] += a[q] * blo(p[q].x); acc[1] += a[q] * bhi(p[q].x);
      acc[2] += a[q] * blo(p[q].y); acc[3] += a[q] * bhi(p[q].y);
      acc[4] += a[q] * blo(p[q].z); acc[5] += a[q] * bhi(p[q].z);
      acc[6] += a[q] * blo(p[q].w); acc[7] += a[q] * bhi(p[q].w);
    }
  }
  for (; j < e1; j += 2) {
    int s0 = col[j];
    float a0 = b2f(Asb[s0 * 16 + h]) + adh;
    uint4 p0 = *(const uint4*)(Hb + (size_t)s0 * 128 + h * 8);
    a0 = (a0 > 0.f) ? a0 : 0.2f * a0;
    float x0 = __expf(a0);
    den += x0;
    acc[0] += x0 * blo(p0.x); acc[1] += x0 * bhi(p0.x);
    acc[2] += x0 * blo(p0.y); acc[3] += x0 * bhi(p0.y);
    acc[4] += x0 * blo(p0.z); acc[5] += x0 * bhi(p0.z);
    acc[6] += x0 * blo(p0.w); acc[7] += x0 * bhi(p0.w);
  }
  // cross-parity reduce (lane ^ 8 within the node's 16-lane group)
  den += __shfl_xor(den, 8);
#pragma unroll
  for (int k = 0; k < 8; ++k) acc[k] += __shfl_xor(acc[k], 8);
  if (par == 0) {
    float inv = 1.f / (den + 1e-16f);
    uint4 o;
    o.x = (unsigned)f2b(acc[0] * inv) | ((unsigned)f2b(acc[1] * inv) << 16);
    o.y = (unsigned)f2b(acc[2] * inv) | ((unsigned)f2b(acc[3] * inv) << 16);
    o.z = (unsigned)f2b(acc[4] * inv) | ((unsigned)f2b(acc[5] * inv) << 16);
    o.w = (unsigned)f2b(acc[6] * inv) | ((unsigned)f2b(acc[7] * inv) << 16);
    *(uint4*)(Vb + (size_t)node * 128 + h * 8) = o;
  }
}

// ---------------- BatchNorm stats: atomic-free two-stage reduce over bf16 V ----------------

#define BN_CHUNK 391   // 128 * 391 = 50048 >= NN

__global__ __launch_bounds__(256) void k_bnreduce(const unsigned short* __restrict__ Vb, float* __restrict__ partS, float* __restrict__ partQ) {
  int t = threadIdx.x;
  int c4 = t & 31, rs = t >> 5;               // 32 channel-quads x 8 row-streams
  int r0 = blockIdx.x * BN_CHUNK + rs;
  int rend = blockIdx.x * BN_CHUNK + BN_CHUNK;
  if (rend > NN) rend = NN;
  float s0 = 0.f, s1 = 0.f, s2 = 0.f, s3 = 0.f;
  float q0 = 0.f, q1 = 0.f, q2 = 0.f, q3 = 0.f;
  for (int r = r0; r < rend; r += 8) {
    uint2 p = *(const uint2*)(Vb + (size_t)r * 128 + c4 * 4);
    float v0 = blo(p.x), v1 = bhi(p.x);
    float v2 = blo(p.y), v3 = bhi(p.y);
    s0 += v0; s1 += v1; s2 += v2; s3 += v3;
    q0 += v0 * v0; q1 += v1 * v1; q2 += v2 * v2; q3 += v3 * v3;
  }
  __shared__ float sm[8][32][8];
  sm[rs][c4][0] = s0; sm[rs][c4][1] = s1; sm[rs][c4][2] = s2; sm[rs][c4][3] = s3;
  sm[rs][c4][4] = q0; sm[rs][c4][5] = q1; sm[rs][c4][6] = q2; sm[rs][c4][7] = q3;
  __syncthreads();
  if (t < 32) {
#pragma unroll
    for (int k = 0; k < 4; ++k) {
      float S = 0.f, Q = 0.f;
#pragma unroll
      for (int r = 0; r < 8; ++r) { S += sm[r][t][k]; Q += sm[r][t][4 + k]; }
      partS[blockIdx.x * 128 + t * 4 + k] = S;
      partQ[blockIdx.x * 128 + t * 4 + k] = Q;
    }
  }
}

__global__ __launch_bounds__(512) void k_bnfin(const float* __restrict__ partS, const float* __restrict__ partQ,
                                               const float* __restrict__ gam, const float* __restrict__ bet,
                                               float* __restrict__ sc) {
  int t = threadIdx.x;
  int c = t & 127, q = (t >> 7) & 1, hf = t >> 8;
  const float* src = q ? partQ : partS;
  float s = 0.f;
#pragma unroll 8
  for (int i = hf * 64; i < hf * 64 + 64; ++i) s += src[i * 128 + c];
  __shared__ float sm[512];
  sm[t] = s;
  __syncthreads();
  if (t < 128) {
    float S = sm[t] + sm[t + 256];
    float Q = sm[t + 128] + sm[t + 384];
    float mean = S * (1.f / NN);
    float var = fmaxf(Q * (1.f / NN) - mean * mean, 0.f);
    float sg = gam[t] * rsqrtf(var + 1e-5f);
    sc[t] = sg;
    sc[128 + t] = bet[t] - mean * sg;
  }
}

// ---------------- pooling (BN+ReLU inline, atomic-free partials) + final ----------------

__global__ __launch_bounds__(256) void k_pool(const unsigned short* __restrict__ Vb, const float* __restrict__ sc,
                                              const int* __restrict__ gstart, float* __restrict__ pp) {
  int g = blockIdx.x >> 2, chunk = blockIdx.x & 3;
  int t = threadIdx.x;
  int c4 = t & 31, rs = t >> 5;
  f4 s = ((const f4*)sc)[c4], sh = ((const f4*)sc)[32 + c4];
  int r0 = gstart[g], r1 = gstart[g + 1];
  float s0 = 0.f, s1 = 0.f, s2 = 0.f, s3 = 0.f;
  for (int r = r0 + chunk + 4 * rs; r < r1; r += 32) {
    uint2 p = *(const uint2*)(Vb + (size_t)r * 128 + c4 * 4);
    s0 += fmaxf(blo(p.x) * s.x + sh.x, 0.f);
    s1 += fmaxf(bhi(p.x) * s.y + sh.y, 0.f);
    s2 += fmaxf(blo(p.y) * s.z + sh.z, 0.f);
    s3 += fmaxf(bhi(p.y) * s.w + sh.w, 0.f);
  }
  __shared__ float sm[8][32][4];
  sm[rs][c4][0] = s0; sm[rs][c4][1] = s1; sm[rs][c4][2] = s2; sm[rs][c4][3] = s3;
  __syncthreads();
  if (t < 32) {
#pragma unroll
    for (int k = 0; k < 4; ++k) {
      float S = 0.f;
#pragma unroll
      for (int r = 0; r < 8; ++r) S += sm[r][t][k];
      pp[(size_t)blockIdx.x * 128 + t * 4 + k] = S;   // partial per (g,chunk)
    }
  }
}

__global__ __launch_bounds__(256) void k_final(const float* __restrict__ pp, const int* __restrict__ gstart,
                                               const float* __restrict__ Wl, const float* __restrict__ bl,
                                               const float* __restrict__ g4, const float* __restrict__ b4,
                                               float* __restrict__ out) {
  int t = threadIdx.x;
  int g = t >> 1, cls = t & 1;
  float cnt = fmaxf((float)(gstart[g + 1] - gstart[g]), 1.f);
  float inv = 1.f / cnt;
  float z = bl[cls];
  for (int f = 0; f < 128; ++f) {
    float ps = pp[(size_t)(g * 4 + 0) * 128 + f] + pp[(size_t)(g * 4 + 1) * 128 + f]
             + pp[(size_t)(g * 4 + 2) * 128 + f] + pp[(size_t)(g * 4 + 3) * 128 + f];
    z += ps * inv * Wl[f * 2 + cls] + ps * Wl[(128 + f) * 2 + cls];
  }
  __shared__ float zs[256];
  __shared__ float st[4];
  zs[t] = z;
  __syncthreads();
  if (t < 2) {
    float s = 0.f, s2 = 0.f;
    for (int gg = 0; gg < 128; ++gg) { float v = zs[gg * 2 + t]; s += v; s2 += v * v; }
    float mean = s * (1.f / 128.f);
    float var = s2 * (1.f / 128.f) - mean * mean;
    var = fmaxf(var, 0.f);
    float sc = g4[t] * rsqrtf(var + 1e-5f);
    st[t] = sc; st[2 + t] = b4[t] - mean * sc;
  }
  __syncthreads();
  out[t] = zs[t] * st[cls] + st[2 + cls];
}

// ---------------- host launcher ----------------

extern "C" void kernel_launch(void* const* d_in, const int* in_sizes, int n_in,
                              void* d_out, int out_size, void* d_ws, size_t ws_size,
                              hipStream_t stream) {
  const float* x     = (const float*)d_in[0];
  const int*   ei    = (const int*)d_in[1];
  const int*   batch = (const int*)d_in[2];
  const float* W[3]    = {(const float*)d_in[3],  (const float*)d_in[9],  (const float*)d_in[15]};
  const float* asrc[3] = {(const float*)d_in[5],  (const float*)d_in[11], (const float*)d_in[17]};
  const float* adst[3] = {(const float*)d_in[6],  (const float*)d_in[12], (const float*)d_in[18]};
  const float* gam[3]  = {(const float*)d_in[7],  (const float*)d_in[13], (const float*)d_in[19]};
  const float* bet[3]  = {(const float*)d_in[8],  (const float*)d_in[14], (const float*)d_in[20]};
  const float* Wl    = (const float*)d_in[21];
  const float* bl    = (const float*)d_in[22];
  const float* g4    = (const float*)d_in[23];
  const float* beta4 = (const float*)d_in[24];

  char* ws = (char*)d_ws;
  size_t off = 0;
  auto alloc = [&](size_t bytes) -> void* {
    void* p = (void*)(ws + off);
    off += (bytes + 255) & ~(size_t)255;
    return p;
  };

  int* row_off  = (int*)alloc((size_t)(NN + 1) * 4);
  int* col      = (int*)alloc((size_t)NEP * 4);
  int* cntmat   = (int*)alloc((size_t)NBLK * NBUK * 4);
  int* btotal   = (int*)alloc((size_t)NBUK * 4);
  int* bbase    = (int*)alloc((size_t)(NBUK + 1) * 4);
  unsigned* pairs = (unsigned*)alloc((size_t)NEP * 4);
  unsigned short* Xb = (unsigned short*)alloc((size_t)NN * 128 * 2);   // layer-0 GEMM input (bf16)
  unsigned short* Hb = (unsigned short*)alloc((size_t)NN * 128 * 2);   // GEMM output (bf16)
  unsigned short* Vb = (unsigned short*)alloc((size_t)NN * 128 * 2);   // agg output, pre-BN (bf16)
  unsigned short* Asb = (unsigned short*)alloc((size_t)NN * 16 * 2);
  float* Ad     = (float*)alloc((size_t)NN * 16 * 4);
  unsigned short* Wt0 = (unsigned short*)alloc((size_t)160 * 128 * 2);
  unsigned short* Wt1 = (unsigned short*)alloc((size_t)160 * 128 * 2);
  unsigned short* Wt2 = (unsigned short*)alloc((size_t)160 * 128 * 2);
  const unsigned short* Wt[3] = {Wt0, Wt1, Wt2};
  float* partS  = (float*)alloc(128 * 128 * 4);
  float* partQ  = (float*)alloc(128 * 128 * 4);
  float* bn_sc  = (float*)alloc(256 * 4);
  float* pp     = (float*)alloc((size_t)NGRAPH * 4 * 128 * 4);
  int* gstart   = (int*)alloc((size_t)(NGRAPH + 1) * 4);

  // ---- front: bucket histogram + all prep work (independent) in one launch ----
  k_front<<<NBLK + CASTB + WTB + WASB + 1, 256, 0, stream>>>(ei, cntmat, x, Xb, W[0], W[1], W[2],
                                                             asrc[0], asrc[1], asrc[2], adst[0], adst[1], adst[2],
                                                             Wt0, Wt1, Wt2, batch, gstart);
  k_bscan<<<NBUK, 512, 0, stream>>>(cntmat, btotal);
  k_bbase<<<1, 512, 0, stream>>>(btotal, bbase);
  k_bscatter<<<NBLK, 256, 0, stream>>>(ei, cntmat, bbase, pairs);
  k_bfinal<<<NBUK, 256, 0, stream>>>(pairs, bbase, row_off, col);

  for (int L = 0; L < 3; ++L) {
    if (L == 0)
      k_gemm_t<0><<<(NN + 127) / 128, 256, 0, stream>>>(Xb, Wt[L], nullptr, Hb, Asb, Ad);
    else
      k_gemm_t<1><<<(NN + 127) / 128, 256, 0, stream>>>(Vb, Wt[L], bn_sc, Hb, Asb, Ad);
    // 3125 node-blocks per channel-half, padded to 8-aligned grid for XCD steering
    k_agg<<<6256, 256, 0, stream>>>(Hb, Asb, Ad, row_off, col, Vb);
    k_bnreduce<<<128, 256, 0, stream>>>(Vb, partS, partQ);
    k_bnfin<<<1, 512, 0, stream>>>(partS, partQ, gam[L], bet[L], bn_sc);
  }

  k_pool<<<NGRAPH * 4, 256, 0, stream>>>(Vb, bn_sc, gstart, pp);   // BN+ReLU fused, atomic-free
  k_final<<<1, 256, 0, stream>>>(pp, gstart, Wl, bl, g4, beta4, (float*)d_out);
}